// Round 1
// baseline (130.245 us; speedup 1.0000x reference)
//
#include <hip/hip_runtime.h>
#include <hip/hip_bf16.h>

#define L_DIM 2048
#define D_DIM 2048
#define B_DIM 2
#define H_DIM 8
#define EPSV 1e-6f

using bf16x8 = __attribute__((ext_vector_type(8))) __bf16;
using f32x4  = __attribute__((ext_vector_type(4))) float;

__device__ inline void gload_lds16(const void* g, void* l) {
    __builtin_amdgcn_global_load_lds(
        (const __attribute__((address_space(1))) void*)g,
        (__attribute__((address_space(3))) void*)l, 16, 0, 0);
}

// round-to-nearest-even f32 -> bf16 (finite inputs)
__device__ inline ushort f2bf(float f) {
    unsigned int u = __float_as_uint(f);
    unsigned int lsb = (u >> 16) & 1u;
    u += 0x7fffu + lsb;
    return (ushort)(u >> 16);
}

// ---------------- K1: row-normalize x, cast to bf16; zero the f64 accumulators --------
__global__ __launch_bounds__(256) void k_normalize(const float* __restrict__ x,
                                                   ushort* __restrict__ xu,
                                                   double* __restrict__ sums) {
    const int row = blockIdx.x;            // b*L + l
    const int t   = threadIdx.x;
    const float* xr = x + (size_t)row * D_DIM;
    float4 v0 = ((const float4*)xr)[t];
    float4 v1 = ((const float4*)xr)[t + 256];
    float ss = v0.x*v0.x + v0.y*v0.y + v0.z*v0.z + v0.w*v0.w
             + v1.x*v1.x + v1.y*v1.y + v1.z*v1.z + v1.w*v1.w;
    #pragma unroll
    for (int off = 32; off; off >>= 1) ss += __shfl_down(ss, off);
    __shared__ float red[4];
    __shared__ float s_inv;
    if ((t & 63) == 0) red[t >> 6] = ss;
    __syncthreads();
    if (t == 0) {
        float nrm = sqrtf(red[0] + red[1] + red[2] + red[3]);
        nrm = fmaxf(nrm, EPSV);
        s_inv = 1.0f / nrm;
    }
    __syncthreads();
    const float inv = s_inv;
    ushort* xo = xu + (size_t)row * D_DIM;
    ushort4 o0, o1;
    o0.x = f2bf(v0.x * inv); o0.y = f2bf(v0.y * inv);
    o0.z = f2bf(v0.z * inv); o0.w = f2bf(v0.w * inv);
    o1.x = f2bf(v1.x * inv); o1.y = f2bf(v1.y * inv);
    o1.z = f2bf(v1.z * inv); o1.w = f2bf(v1.w * inv);
    ((ushort4*)xo)[t]       = o0;
    ((ushort4*)xo)[t + 256] = o1;
    if (row == 0 && t < 4) sums[t] = 0.0;   // runs before K2 in stream order
}

// ---------------- K2: K = Xu * Xu^T (bf16 MFMA, 128x128 tile, BK=32) -----------------
__global__ __launch_bounds__(256) void k_gemm(const ushort* __restrict__ Xu,
                                              float* __restrict__ Kout,
                                              double* __restrict__ sums) {
    __shared__ __align__(16) ushort lds_a[128 * 32];
    __shared__ __align__(16) ushort lds_b[128 * 32];
    const int t    = threadIdx.x;
    const int lane = t & 63;
    const int w    = t >> 6;
    const int wr   = w >> 1, wc = w & 1;       // 2x2 waves, 64x64 each
    const int bRow = blockIdx.x * 128;
    const int bCol = blockIdx.y * 128;
    const int batch = blockIdx.z;
    const ushort* Xb = Xu + (size_t)batch * L_DIM * D_DIM;

    const int srow = t >> 2;                   // 0..63
    const int scol = (t & 3) * 8;              // bf16 element offset within 32-wide k-slab
    const ushort* gA0 = Xb + (size_t)(bRow + srow)      * D_DIM + scol;
    const ushort* gA1 = Xb + (size_t)(bRow + 64 + srow) * D_DIM + scol;
    const ushort* gB0 = Xb + (size_t)(bCol + srow)      * D_DIM + scol;
    const ushort* gB1 = Xb + (size_t)(bCol + 64 + srow) * D_DIM + scol;
    ushort* lA0 = lds_a + t * 8;
    ushort* lA1 = lds_a + 64 * 32 + t * 8;
    ushort* lB0 = lds_b + t * 8;
    ushort* lB1 = lds_b + 64 * 32 + t * 8;

    f32x4 acc[4][4] = {};
    const int frow = lane & 15;
    const int fk   = lane >> 4;

    for (int kt = 0; kt < D_DIM / 32; ++kt) {
        __syncthreads();                       // protect LDS before overwrite
        const size_t ko = (size_t)kt * 32;
        gload_lds16(gA0 + ko, lA0);
        gload_lds16(gA1 + ko, lA1);
        gload_lds16(gB0 + ko, lB0);
        gload_lds16(gB1 + ko, lB1);
        __syncthreads();                       // compiler emits vmcnt(0) drain
        bf16x8 a[4], b[4];
        #pragma unroll
        for (int m = 0; m < 4; ++m)
            a[m] = *(const bf16x8*)&lds_a[(wr * 64 + m * 16 + frow) * 32 + fk * 8];
        #pragma unroll
        for (int n = 0; n < 4; ++n)
            b[n] = *(const bf16x8*)&lds_b[(wc * 64 + n * 16 + frow) * 32 + fk * 8];
        #pragma unroll
        for (int m = 0; m < 4; ++m)
            #pragma unroll
            for (int n = 0; n < 4; ++n)
                acc[m][n] = __builtin_amdgcn_mfma_f32_16x16x32_bf16(a[m], b[n], acc[m][n], 0, 0, 0);
    }

    float* Kb = Kout + (size_t)batch * L_DIM * L_DIM;
    float ps = 0.f, pss = 0.f;
    #pragma unroll
    for (int m = 0; m < 4; ++m) {
        #pragma unroll
        for (int n = 0; n < 4; ++n) {
            #pragma unroll
            for (int j = 0; j < 4; ++j) {
                const int r = bRow + wr * 64 + m * 16 + fk * 4 + j;
                const int c = bCol + wc * 64 + n * 16 + frow;
                const float v = acc[m][n][j];
                Kb[(size_t)r * L_DIM + c] = v;
                ps += v; pss += v * v;
            }
        }
    }
    #pragma unroll
    for (int off = 32; off; off >>= 1) {
        ps  += __shfl_down(ps, off);
        pss += __shfl_down(pss, off);
    }
    __shared__ float redS[4], redSS[4];
    if (lane == 0) { redS[w] = ps; redSS[w] = pss; }
    __syncthreads();
    if (t == 0) {
        atomicAdd(&sums[batch * 2],     (double)(redS[0] + redS[1] + redS[2] + redS[3]));
        atomicAdd(&sums[batch * 2 + 1], (double)(redSS[0] + redSS[1] + redSS[2] + redSS[3]));
    }
}

// ---------------- K3: K_norm in-place, head-mean(attn) dot, gate ----------------------
__global__ __launch_bounds__(256) void k_epilogue(const float* __restrict__ attn,
                                                  float* __restrict__ out,
                                                  const double* __restrict__ sums,
                                                  const float* __restrict__ Wp,
                                                  const float* __restrict__ bp) {
    const int row = blockIdx.x;              // b*L + l
    const int b = row >> 11;
    const int l = row & (L_DIM - 1);
    const int t = threadIdx.x;

    const double N = (double)L_DIM * (double)L_DIM;
    const double mean_d = sums[b * 2] / N;
    double var = (sums[b * 2 + 1] - N * mean_d * mean_d) / (N - 1.0);
    var = var > 0.0 ? var : 0.0;
    float sd = (float)sqrt(var);
    sd = fmaxf(sd, EPSV);
    const float inv_std = 1.0f / sd;
    const float mean = (float)mean_d;

    float* Krow = out + 2 * B_DIM * L_DIM + ((size_t)b * L_DIM + l) * L_DIM;
    const float* abase = attn + ((size_t)b * H_DIM * L_DIM + l) * L_DIM;

    float dot = 0.f;
    #pragma unroll
    for (int it = 0; it < 2; ++it) {
        const int i = t * 4 + it * 1024;
        float4 kv = *(const float4*)&Krow[i];
        float4 kn;
        kn.x = (kv.x - mean) * inv_std;
        kn.y = (kv.y - mean) * inv_std;
        kn.z = (kv.z - mean) * inv_std;
        kn.w = (kv.w - mean) * inv_std;
        *(float4*)&Krow[i] = kn;
        float ax = 0.f, ay = 0.f, az = 0.f, aw = 0.f;
        #pragma unroll
        for (int h = 0; h < H_DIM; ++h) {
            const float4 av = *(const float4*)&abase[(size_t)h * L_DIM * L_DIM + i];
            ax += av.x; ay += av.y; az += av.z; aw += av.w;
        }
        dot += 0.125f * (ax * kn.x + ay * kn.y + az * kn.z + aw * kn.w);
    }
    #pragma unroll
    for (int off = 32; off; off >>= 1) dot += __shfl_down(dot, off);
    __shared__ float red[4];
    if ((t & 63) == 0) red[t >> 6] = dot;
    __syncthreads();
    if (t == 0) {
        const float ca = red[0] + red[1] + red[2] + red[3];
        out[B_DIM * L_DIM + row] = ca;                    // cos_align
        const float z = Wp[0] * ca + bp[0];
        out[row] = 1.0f / (1.0f + expf(-z));              // gate
    }
}

extern "C" void kernel_launch(void* const* d_in, const int* in_sizes, int n_in,
                              void* d_out, int out_size, void* d_ws, size_t ws_size,
                              hipStream_t stream) {
    const float* x    = (const float*)d_in[0];
    const float* attn = (const float*)d_in[1];
    const float* W    = (const float*)d_in[2];
    const float* bb   = (const float*)d_in[3];
    float* out = (float*)d_out;

    ushort* xu   = (ushort*)d_ws;                                         // 16 MiB bf16 x_unit
    double* sums = (double*)((char*)d_ws + (size_t)B_DIM * L_DIM * D_DIM * 2);
    float*  Kbuf = out + 2 * B_DIM * L_DIM;                               // K lives in K_norm slot

    hipLaunchKernelGGL(k_normalize, dim3(B_DIM * L_DIM), dim3(256), 0, stream, x, xu, sums);
    hipLaunchKernelGGL(k_gemm, dim3(L_DIM / 128, L_DIM / 128, B_DIM), dim3(256), 0, stream,
                       xu, Kbuf, sums);
    hipLaunchKernelGGL(k_epilogue, dim3(B_DIM * L_DIM), dim3(256), 0, stream,
                       attn, out, sums, W, bb);
}